// Round 11
// baseline (252.670 us; speedup 1.0000x reference)
//
#include <hip/hip_runtime.h>
#include <hip/hip_bf16.h>
#include <math.h>

#define S_LEN 4096
#define EMB   1024
#define NHEAD 16
#define HDIM  64

typedef __attribute__((ext_vector_type(8))) _Float16 half8;
typedef __attribute__((ext_vector_type(4))) _Float16 half4;
typedef __attribute__((ext_vector_type(4))) float float4_t;
typedef __attribute__((ext_vector_type(16))) float float16_t;
typedef __attribute__((ext_vector_type(4))) int int4_t;
typedef __attribute__((ext_vector_type(2))) int int2_t;

#define GLOBAL_AS(p) ((const __attribute__((address_space(1))) void*)(p))
#define LDS_AS(p)    ((__attribute__((address_space(3))) void*)(p))

#define LOG2E 1.4426950408889634f

// ---------------------------------------------------------------------------
// fused prep: blocks [0,4096) convert x fp32->fp16; [4096,4864) transpose
// Wqkv [1024,3072] -> WTh [3072,1024]; [4864,5120) transpose Wp -> WpT.
// ---------------------------------------------------------------------------
__global__ __launch_bounds__(256) void prep(
    const float* __restrict__ x, const float* __restrict__ Wqkv,
    const float* __restrict__ Wp,
    _Float16* __restrict__ xh, _Float16* __restrict__ WTh,
    _Float16* __restrict__ WpT)
{
    const int bid = blockIdx.x;
    if (bid < 4096) {
        const int i = bid * 256 + threadIdx.x;
        const float4_t v = ((const float4_t*)x)[i];
        half4 hh;
#pragma unroll
        for (int j = 0; j < 4; ++j) hh[j] = (_Float16)v[j];
        ((half4*)xh)[i] = hh;
        return;
    }
    __shared__ float t[64][65];
    const float* in;
    _Float16* out;
    int R, C, bx, by;
    if (bid < 4096 + 768) {
        const int idx = bid - 4096;
        bx = idx % 48; by = idx / 48;
        in = Wqkv; out = WTh; R = 1024; C = 3072;
    } else {
        const int idx = bid - 4864;
        bx = idx & 15; by = idx >> 4;
        in = Wp; out = WpT; R = 1024; C = 1024;
    }
    const int r0 = by * 64, c0 = bx * 64;
    for (int i = threadIdx.x; i < 64 * 64; i += 256) {
        int r = i >> 6, c = i & 63;
        t[r][c] = in[(size_t)(r0 + r) * C + c0 + c];
    }
    __syncthreads();
    for (int i = threadIdx.x; i < 64 * 64; i += 256) {
        int c = i >> 6, r = i & 63;
        out[(size_t)(c0 + c) * R + r0 + r] = (_Float16)t[r][c];
    }
}

// ---------------------------------------------------------------------------
// QKV GEMM, plain fp16, m97 structure: 128x128 tile, BK=32, global_load_lds.
// XCD-bijective block swizzle (T1): 768 = 96/XCD, contiguous tile spans.
// Epilogue: cols<1024 -> q plane; 1024..2047 -> k plane SCALED by log2(e);
// cols>=2048 -> fp16 V^T [1024,4096], packed half4 along s.
// ---------------------------------------------------------------------------
__global__ __launch_bounds__(256) void gemm_qkv(
    const _Float16* __restrict__ Ag, const _Float16* __restrict__ Bg,
    const float* __restrict__ bias,
    _Float16* __restrict__ qk, _Float16* __restrict__ vt, int K)
{
    constexpr int BK = 32;
    __shared__ _Float16 Ah[128 * BK];
    __shared__ _Float16 Bh[128 * BK];

    const int tid = threadIdx.x;
    const int wave = tid >> 6, lane = tid & 63;
    const int l16 = lane & 15, quad = lane >> 4;
    const int wr = wave >> 1, wc = wave & 1;
    const int lid = blockIdx.y * 24 + blockIdx.x;      // 0..767
    const int swz = (lid & 7) * 96 + (lid >> 3);       // bijective (768%8==0)
    const int row0 = (swz / 24) * 128, col0 = (swz % 24) * 128;
    const int lrow = lane >> 2, lc8 = (lane & 3) * 8;

    float4_t acc[4][4];
#pragma unroll
    for (int i = 0; i < 4; ++i)
#pragma unroll
        for (int j = 0; j < 4; ++j) acc[i][j] = (float4_t){0.f, 0.f, 0.f, 0.f};

    for (int k0 = 0; k0 < K; k0 += BK) {
        __syncthreads();
#pragma unroll
        for (int i = 0; i < 2; ++i) {
            const int ar = i * 64 + wave * 16;
            __builtin_amdgcn_global_load_lds(
                GLOBAL_AS(Ag + (size_t)(row0 + ar + lrow) * K + k0 + lc8),
                LDS_AS(&Ah[ar * BK]), 16, 0, 0);
            __builtin_amdgcn_global_load_lds(
                GLOBAL_AS(Bg + (size_t)(col0 + ar + lrow) * K + k0 + lc8),
                LDS_AS(&Bh[ar * BK]), 16, 0, 0);
        }
        __syncthreads();

        half8 af[4], bfr[4];
#pragma unroll
        for (int t = 0; t < 4; ++t) {
            af[t]  = *(const half8*)&Ah[(wr * 64 + t * 16 + l16) * BK + quad * 8];
            bfr[t] = *(const half8*)&Bh[(wc * 64 + t * 16 + l16) * BK + quad * 8];
        }
#pragma unroll
        for (int i = 0; i < 4; ++i)
#pragma unroll
            for (int j = 0; j < 4; ++j)
                acc[i][j] = __builtin_amdgcn_mfma_f32_16x16x32_f16(af[i], bfr[j], acc[i][j], 0, 0, 0);
    }

#pragma unroll
    for (int i = 0; i < 4; ++i) {
#pragma unroll
        for (int j = 0; j < 4; ++j) {
            const int colb = col0 + wc * 64 + j * 16 + l16;
            const float bv = bias[colb];
            const int rowb = row0 + wr * 64 + i * 16 + quad * 4;
            if (colb < 2048) {
                const float sc = (colb >= 1024) ? LOG2E : 1.0f;
#pragma unroll
                for (int r = 0; r < 4; ++r)
                    qk[(size_t)(rowb + r) * 2048 + colb] =
                        (_Float16)((acc[i][j][r] + bv) * sc);
            } else {
                half4 w;
#pragma unroll
                for (int r = 0; r < 4; ++r) w[r] = (_Float16)(acc[i][j][r] + bv);
                *(half4*)&vt[(size_t)(colb - 2048) * 4096 + rowb] = w;
            }
        }
    }
}

// ---------------------------------------------------------------------------
// Out-projection GEMM, fp16, 128(M)x64(N) tile -> 512 blocks (2/CU).
// XCD-bijective swizzle (512%8==0, 64 blocks/XCD contiguous span).
// ---------------------------------------------------------------------------
__global__ __launch_bounds__(256) void gemm_out(
    const _Float16* __restrict__ Ag, const _Float16* __restrict__ Bg,
    const float* __restrict__ bias, float* __restrict__ C, int N, int K)
{
    constexpr int BK = 32;
    __shared__ _Float16 Ah[128 * BK];
    __shared__ _Float16 Bh[64 * BK];

    const int tid = threadIdx.x;
    const int wave = tid >> 6, lane = tid & 63;
    const int l16 = lane & 15, quad = lane >> 4;
    const int lid = blockIdx.y * 16 + blockIdx.x;      // 0..511
    const int swz = (lid & 7) * 64 + (lid >> 3);       // bijective (512%8==0)
    const int row0 = (swz / 16) * 128, col0 = (swz % 16) * 64;
    const int lrow = lane >> 2, lc8 = (lane & 3) * 8;

    float4_t acc[2][4];
#pragma unroll
    for (int i = 0; i < 2; ++i)
#pragma unroll
        for (int j = 0; j < 4; ++j) acc[i][j] = (float4_t){0.f, 0.f, 0.f, 0.f};

    for (int k0 = 0; k0 < K; k0 += BK) {
        __syncthreads();
#pragma unroll
        for (int i = 0; i < 2; ++i) {
            const int ar = i * 64 + wave * 16;
            __builtin_amdgcn_global_load_lds(
                GLOBAL_AS(Ag + (size_t)(row0 + ar + lrow) * K + k0 + lc8),
                LDS_AS(&Ah[ar * BK]), 16, 0, 0);
        }
        {
            const int br = wave * 16;
            __builtin_amdgcn_global_load_lds(
                GLOBAL_AS(Bg + (size_t)(col0 + br + lrow) * K + k0 + lc8),
                LDS_AS(&Bh[br * BK]), 16, 0, 0);
        }
        __syncthreads();

        half8 af[2], bfr[4];
#pragma unroll
        for (int t = 0; t < 2; ++t)
            af[t] = *(const half8*)&Ah[(wave * 32 + t * 16 + l16) * BK + quad * 8];
#pragma unroll
        for (int t = 0; t < 4; ++t)
            bfr[t] = *(const half8*)&Bh[(t * 16 + l16) * BK + quad * 8];
#pragma unroll
        for (int i = 0; i < 2; ++i)
#pragma unroll
            for (int j = 0; j < 4; ++j)
                acc[i][j] = __builtin_amdgcn_mfma_f32_16x16x32_f16(af[i], bfr[j], acc[i][j], 0, 0, 0);
    }

#pragma unroll
    for (int i = 0; i < 2; ++i) {
#pragma unroll
        for (int j = 0; j < 4; ++j) {
            const int colb = col0 + j * 16 + l16;
            const float bv = bias[colb];
#pragma unroll
            for (int r = 0; r < 4; ++r) {
                const int row = row0 + wave * 32 + i * 16 + quad * 4 + r;
                C[(size_t)row * N + colb] = acc[i][j][r] + bv;
            }
        }
    }
}

// ---------------------------------------------------------------------------
// MFMA causal flash attention — round-6 schedule + DOUBLE-GRANULARITY STAGING
// (resubmit of round 10; that bench died on container acquisition, not on the
// kernel — code re-audited: uniform barriers, L=1 edge OK, 64KB LDS / 2
// blocks/CU OK).
// Rounds 7-9: all concurrency-scheduling refinements netted <=0 (traffic/
// overhead ate the TLP gain). Flash is pinned by PER-ITERATION cost: ~2430
// cy/block-iter, one barrier + vmcnt(0) DMA-drain per 64-key tile (~20%
// slice), 31-deep serial fmax chain (~124cy dep) every iter.
// On the PROVEN round-6 2-way split-K quartet schedule (66.9us, 31MB):
//  (1) KVBLK=128 staging: TWO 64-key sub-tiles per barrier into 2-wide
//      double-buffered LDS (64KB, 2 blocks/CU = 8 waves/CU sustained ≈
//      round-6's measured average). Halves barrier+drain events; drained
//      DMA gets a 2-body compute phase of slack. Inner 64-key body is
//      BIT-IDENTICAL to rounds 5-9.
//  (2) Tree-reduced softmax max & lsum (depth ~6 vs 31-serial; fp max/add
//      not compiler-reassociated; ~100cy off the per-iter critical path).
// Kept: 2-way split-K (stride 128), quartet CU-pairing, XOR-swizzled DMA
// staging (slot(row,col8)=row*8+(col8^(row&7))), S^T=K Q^T log2-domain
// 32x32 MFMA, cvt_pkrtz+permlane32_swap P-exchange, defer-max (T13),
// setprio (T5), XCD-pinned heads; unnormalized partials+(m,l), 2-slot
// combine.
// ---------------------------------------------------------------------------
__global__ __launch_bounds__(256, 2) void flash_attn_f16(
    const _Float16* __restrict__ qk, const _Float16* __restrict__ v_t,
    _Float16* __restrict__ opart, float* __restrict__ mlpart)
{
    __shared__ __align__(16) _Float16 KsT[2][2][64 * 64];  // [buf][sub][slot*8]
    __shared__ __align__(16) _Float16 VtT[2][2][64 * 64];

    const int bid  = blockIdx.x;
    const int g    = bid & 255;                 // residency group (CU)
    const int hv   = g & 15;
    const int h    = (hv & 7) * 2 + (hv >> 3);  // XCD-pinned heads
    const int j    = g >> 4;                    // 0..15
    const int v    = bid >> 8;                  // 0..3
    const int tile = (v & 1) ? (31 - j) : j;    // quartet sums to 66 iters
    const int split= v >> 1;                    // 0: even k-tiles, 1: odd

    const int wave = threadIdx.x >> 6;          // 0..3
    const int lane = threadIdx.x & 63;
    const int l31  = lane & 31;
    const int hi   = lane >> 5;                 // 0/1

    // DMA source-address components (lane's LDS slot is wave*128+p*64+lane):
    const int dma_r = wave * 16 + (lane >> 3);             // row  (+ p*8)
    const int dma_c = ((lane & 7) ^ (lane >> 3)) * 8;      // logical col (halfs)

    const _Float16* kplane = qk + 1024 + h * HDIM;
    const _Float16* vplane = v_t + (size_t)h * HDIM * 4096;

    const int q0 = tile * 128 + wave * 32;

    // ---- Q fragment (B-operand of 32x32x16): col=q=l31, k=16j+8*hi ------
    half8 qf[4];
#pragma unroll
    for (int jj = 0; jj < 4; ++jj)
        qf[jj] = *(const half8*)(qk + (size_t)(q0 + l31) * 2048 + h * HDIM
                                 + jj * 16 + hi * 8);

    float16_t o0 = (float16_t)0.f, o1 = (float16_t)0.f;
    float m_r = -INFINITY, l_r = 0.f;

    const int kb0 = 64 * split;
    const int L   = tile + 1;        // k-iters, stride 128
    const int S   = (L + 1) >> 1;    // stages (2 iters each)

    // stage one 64-key sub-tile (k-offset kbv) into [ibuf][sub]
    auto stage1 = [&](int ibuf, int sub, int kbv) {
#pragma unroll
        for (int p = 0; p < 2; ++p) {
            const int r = dma_r + p * 8;
            __builtin_amdgcn_global_load_lds(
                GLOBAL_AS(kplane + (size_t)(kbv + r) * 2048 + dma_c),
                LDS_AS(&KsT[ibuf][sub][(wave * 128 + p * 64) * 8]), 16, 0, 0);
            __builtin_amdgcn_global_load_lds(
                GLOBAL_AS(vplane + (size_t)r * 4096 + kbv + dma_c),
                LDS_AS(&VtT[ibuf][sub][(wave * 128 + p * 64) * 8]), 16, 0, 0);
        }
    };

    // 64-key compute body — identical math to rounds 5-9
    auto body = [&](int ibuf, int sub, int kb) {
        if (kb > q0 + 31) return;    // fully-masked for this wave
        const _Float16* Ks = &KsT[ibuf][sub][0];
        const _Float16* Vs = &VtT[ibuf][sub][0];

        // ---- S^T = K Q^T (log2-domain logits), 2 key-chunks --------------
        float16_t s0 = (float16_t)0.f, s1 = (float16_t)0.f;
        __builtin_amdgcn_s_setprio(1);
#pragma unroll
        for (int jj = 0; jj < 4; ++jj) {
            const int r7 = l31 & 7;
            const half8 kf0 = *(const half8*)&Ks[((l31) * 8 + ((2 * jj + hi) ^ r7)) * 8];
            const half8 kf1 = *(const half8*)&Ks[((32 + l31) * 8 + ((2 * jj + hi) ^ r7)) * 8];
            s0 = __builtin_amdgcn_mfma_f32_32x32x16_f16(kf0, qf[jj], s0, 0, 0, 0);
            s1 = __builtin_amdgcn_mfma_f32_32x32x16_f16(kf1, qf[jj], s1, 0, 0, 0);
        }
        __builtin_amdgcn_s_setprio(0);

        // ---- causal mask (diagonal-straddling tile only) ------------------
        if (kb + 63 > q0) {
            const int qg = q0 + l31;
#pragma unroll
            for (int gg = 0; gg < 4; ++gg)
#pragma unroll
                for (int r = 0; r < 4; ++r) {
                    const int keyb = kb + r + 8 * gg + 4 * hi;
                    if (keyb > qg)      s0[4 * gg + r] = -INFINITY;
                    if (keyb + 32 > qg) s1[4 * gg + r] = -INFINITY;
                }
        }

        // ---- online softmax: TREE max (depth ~6) + ONE shfl, defer-max ----
        float a0 = fmaxf(s0[0], s0[1]),  a1 = fmaxf(s0[2], s0[3]);
        float a2 = fmaxf(s0[4], s0[5]),  a3 = fmaxf(s0[6], s0[7]);
        float a4 = fmaxf(s0[8], s0[9]),  a5 = fmaxf(s0[10], s0[11]);
        float a6 = fmaxf(s0[12], s0[13]), a7 = fmaxf(s0[14], s0[15]);
        float b0 = fmaxf(s1[0], s1[1]),  b1 = fmaxf(s1[2], s1[3]);
        float b2 = fmaxf(s1[4], s1[5]),  b3 = fmaxf(s1[6], s1[7]);
        float b4 = fmaxf(s1[8], s1[9]),  b5 = fmaxf(s1[10], s1[11]);
        float b6 = fmaxf(s1[12], s1[13]), b7 = fmaxf(s1[14], s1[15]);
        a0 = fmaxf(a0, a1); a2 = fmaxf(a2, a3); a4 = fmaxf(a4, a5); a6 = fmaxf(a6, a7);
        b0 = fmaxf(b0, b1); b2 = fmaxf(b2, b3); b4 = fmaxf(b4, b5); b6 = fmaxf(b6, b7);
        a0 = fmaxf(a0, a2); a4 = fmaxf(a4, a6); b0 = fmaxf(b0, b2); b4 = fmaxf(b4, b6);
        float mx = fmaxf(fmaxf(a0, a4), fmaxf(b0, b4));
        mx = fmaxf(mx, __shfl_xor(mx, 32));
        const bool  grow  = mx > m_r + 8.0f;
        const float mnew  = grow ? mx : m_r;
        const float alpha = __builtin_amdgcn_exp2f(m_r - mnew);  // ==1 if !grow

        // ---- P = exp2(S - m), pack to fp16 words; tree lsum ---------------
        int w0[8], w1[8];
        float ls0 = 0.f, ls1 = 0.f, ls2 = 0.f, ls3 = 0.f;
#pragma unroll
        for (int i = 0; i < 8; ++i) {
            const float pa = __builtin_amdgcn_exp2f(s0[2 * i]     - mnew);
            const float pb = __builtin_amdgcn_exp2f(s0[2 * i + 1] - mnew);
            if (i & 1) ls1 += pa + pb; else ls0 += pa + pb;
            w0[i] = __builtin_bit_cast(int, __builtin_amdgcn_cvt_pkrtz(pa, pb));
        }
#pragma unroll
        for (int i = 0; i < 8; ++i) {
            const float pa = __builtin_amdgcn_exp2f(s1[2 * i]     - mnew);
            const float pb = __builtin_amdgcn_exp2f(s1[2 * i + 1] - mnew);
            if (i & 1) ls3 += pa + pb; else ls2 += pa + pb;
            w1[i] = __builtin_bit_cast(int, __builtin_amdgcn_cvt_pkrtz(pa, pb));
        }
        const float lsum = (ls0 + ls1) + (ls2 + ls3);
        l_r = l_r * alpha + lsum;   // per-lane partial (alpha row-uniform)
        m_r = mnew;
        if (__any(grow)) {
#pragma unroll
            for (int i = 0; i < 16; ++i) { o0[i] *= alpha; o1[i] *= alpha; }
        }

        // ---- P -> B-operand frags via permlane32_swap (no LDS) ------------
        half8 pf[4];
        {
            const int2_t c02 = __builtin_amdgcn_permlane32_swap(w0[0], w0[2], 0, 0);
            const int2_t c13 = __builtin_amdgcn_permlane32_swap(w0[1], w0[3], 0, 0);
            const int2_t c46 = __builtin_amdgcn_permlane32_swap(w0[4], w0[6], 0, 0);
            const int2_t c57 = __builtin_amdgcn_permlane32_swap(w0[5], w0[7], 0, 0);
            int4_t f0 = {c02[0], c13[0], c02[1], c13[1]};
            int4_t f1 = {c46[0], c57[0], c46[1], c57[1]};
            pf[0] = __builtin_bit_cast(half8, f0);
            pf[1] = __builtin_bit_cast(half8, f1);
            const int2_t d02 = __builtin_amdgcn_permlane32_swap(w1[0], w1[2], 0, 0);
            const int2_t d13 = __builtin_amdgcn_permlane32_swap(w1[1], w1[3], 0, 0);
            const int2_t d46 = __builtin_amdgcn_permlane32_swap(w1[4], w1[6], 0, 0);
            const int2_t d57 = __builtin_amdgcn_permlane32_swap(w1[5], w1[7], 0, 0);
            int4_t f2 = {d02[0], d13[0], d02[1], d13[1]};
            int4_t f3 = {d46[0], d57[0], d46[1], d57[1]};
            pf[2] = __builtin_bit_cast(half8, f2);
            pf[3] = __builtin_bit_cast(half8, f3);
        }

        // ---- O^T += V^T P^T -----------------------------------------------
        __builtin_amdgcn_s_setprio(1);
#pragma unroll
        for (int kc = 0; kc < 4; ++kc) {
            const int r7 = l31 & 7;
            const half8 vf0 = *(const half8*)&Vs[((l31) * 8 + ((2 * kc + hi) ^ r7)) * 8];
            const half8 vf1 = *(const half8*)&Vs[((32 + l31) * 8 + ((2 * kc + hi) ^ r7)) * 8];
            o0 = __builtin_amdgcn_mfma_f32_32x32x16_f16(vf0, pf[kc], o0, 0, 0, 0);
            o1 = __builtin_amdgcn_mfma_f32_32x32x16_f16(vf1, pf[kc], o1, 0, 0, 0);
        }
        __builtin_amdgcn_s_setprio(0);
    };

    // ---- prologue: pre-stage stage 0 (k-iters 0 and 1) into buf 0 ---------
    stage1(0, 0, kb0);
    if (1 < L) stage1(0, 1, kb0 + 128);

    int ib = 0;
    for (int st = 0; st < S; ++st, ib ^= 1) {
        __syncthreads();   // DMA(buf ib) done (vmcnt drain) + readers done

        if (st + 1 < S) {  // async DMA of next stage (2 sub-tiles) into buf^1
            const int i2 = 2 * (st + 1);
            stage1(ib ^ 1, 0, kb0 + 128 * i2);
            if (i2 + 1 < L) stage1(ib ^ 1, 1, kb0 + 128 * (i2 + 1));
        }

        body(ib, 0, kb0 + 256 * st);
        if (2 * st + 1 < L) body(ib, 1, kb0 + 256 * st + 128);
    }

    // ---- epilogue: store UNNORMALIZED partials + (m, l) -------------------
    const float lr = l_r + __shfl_xor(l_r, 32);
    const size_t prow = (size_t)(split * 4096 + q0 + l31);
#pragma unroll
    for (int gg = 0; gg < 4; ++gg) {
        half4 wa, wb;
#pragma unroll
        for (int r = 0; r < 4; ++r) {
            wa[r] = (_Float16)o0[4 * gg + r];
            wb[r] = (_Float16)o1[4 * gg + r];
        }
        const size_t base = prow * 1024 + h * HDIM + 8 * gg + 4 * hi;
        *(half4*)&opart[base]      = wa;
        *(half4*)&opart[base + 32] = wb;
    }
    if (hi == 0) {
        float2 ml; ml.x = m_r; ml.y = lr;
        ((float2*)mlpart)[prow * 16 + h] = ml;
    }
}

// ---------------------------------------------------------------------------
// combine: merge the two split-K partials per (row, head); write resh fp16.
// 524288 threads, one half8 of d-values each. ~25 MB traffic, ~6 us.
// ---------------------------------------------------------------------------
__global__ __launch_bounds__(256) void combine(
    const _Float16* __restrict__ opart, const float* __restrict__ mlpart,
    _Float16* __restrict__ resh)
{
    const int idx = blockIdx.x * 256 + threadIdx.x;   // 0..524287
    const int row = idx >> 7;                          // 0..4095
    const int c8  = (idx & 127) * 8;                   // d-offset in the row
    const int h   = c8 >> 6;
    const float2 ml0 = ((const float2*)mlpart)[(size_t)row * 16 + h];
    const float2 ml1 = ((const float2*)mlpart)[(size_t)(4096 + row) * 16 + h];
    const float m  = fmaxf(ml0.x, ml1.x);              // m0 always finite
    const float a0 = __builtin_amdgcn_exp2f(ml0.x - m);
    const float a1 = __builtin_amdgcn_exp2f(ml1.x - m);  // 0 if m1 = -inf
    const float inv = 1.0f / (ml0.y * a0 + ml1.y * a1);  // l0 > 0 always
    const half8 o0 = *(const half8*)&opart[(size_t)row * 1024 + c8];
    const half8 o1 = *(const half8*)&opart[(size_t)(4096 + row) * 1024 + c8];
    half8 w;
#pragma unroll
    for (int jj = 0; jj < 8; ++jj)
        w[jj] = (_Float16)(((float)o0[jj] * a0 + (float)o1[jj] * a1) * inv);
    *(half8*)&resh[(size_t)row * 1024 + c8] = w;
}

// ---------------------------------------------------------------------------
// launch
// ---------------------------------------------------------------------------
extern "C" void kernel_launch(void* const* d_in, const int* in_sizes, int n_in,
                              void* d_out, int out_size, void* d_ws, size_t ws_size,
                              hipStream_t stream)
{
    const float* x    = (const float*)d_in[0];
    const float* Wqkv = (const float*)d_in[2];
    const float* bqkv = (const float*)d_in[3];
    const float* Wp   = (const float*)d_in[4];
    const float* bp   = (const float*)d_in[5];
    float* out = (float*)d_out;

    _Float16* xh  = (_Float16*)d_ws;                 // [4096,1024] fp16  8MB
    _Float16* WTh = xh + (size_t)4096 * 1024;        // [3072,1024] fp16  6MB
    _Float16* qkh = WTh + (size_t)3072 * 1024;       // [4096,2048] fp16 16MB
    _Float16* vtg = qkh + (size_t)4096 * 2048;       // V^T [1024,4096]   8MB
    _Float16* WpT = vtg + (size_t)1024 * 4096;       // [1024,1024] fp16  2MB
    _Float16* opart = WpT + (size_t)1024 * 1024;     // [2,4096,1024] fp16 16MB
    float* mlpart = (float*)(opart + (size_t)2 * 4096 * 1024);  // [2,4096,16,2] f32 1MB
    _Float16* resh = xh;            // alias: x fp16 dead after QKV GEMM

    dim3 blk(256);

    prep<<<dim3(5120), blk, 0, stream>>>(x, Wqkv, Wp, xh, WTh, WpT);

    gemm_qkv<<<dim3(3072 / 128, 4096 / 128), blk, 0, stream>>>(
        xh, WTh, bqkv, qkh, vtg, 1024);

    flash_attn_f16<<<dim3(1024), dim3(256), 0, stream>>>(qkh, vtg, opart, mlpart);

    combine<<<dim3(2048), blk, 0, stream>>>(opart, mlpart, resh);

    gemm_out<<<dim3(1024 / 64, 4096 / 128), blk, 0, stream>>>(
        resh, WpT, bp, out, 1024, 1024);
}

// Round 12
// 244.291 us; speedup vs baseline: 1.0343x; 1.0343x over previous
//
#include <hip/hip_runtime.h>
#include <hip/hip_bf16.h>
#include <math.h>

#define S_LEN 4096
#define EMB   1024
#define NHEAD 16
#define HDIM  64

typedef __attribute__((ext_vector_type(8))) _Float16 half8;
typedef __attribute__((ext_vector_type(4))) _Float16 half4;
typedef __attribute__((ext_vector_type(4))) float float4_t;
typedef __attribute__((ext_vector_type(16))) float float16_t;
typedef __attribute__((ext_vector_type(4))) int int4_t;
typedef __attribute__((ext_vector_type(2))) int int2_t;

#define GLOBAL_AS(p) ((const __attribute__((address_space(1))) void*)(p))
#define LDS_AS(p)    ((__attribute__((address_space(3))) void*)(p))

#define LOG2E 1.4426950408889634f

// ---------------------------------------------------------------------------
// fused prep: blocks [0,4096) convert x fp32->fp16; [4096,4864) transpose
// Wqkv [1024,3072] -> WTh [3072,1024]; [4864,5120) transpose Wp -> WpT.
// ---------------------------------------------------------------------------
__global__ __launch_bounds__(256) void prep(
    const float* __restrict__ x, const float* __restrict__ Wqkv,
    const float* __restrict__ Wp,
    _Float16* __restrict__ xh, _Float16* __restrict__ WTh,
    _Float16* __restrict__ WpT)
{
    const int bid = blockIdx.x;
    if (bid < 4096) {
        const int i = bid * 256 + threadIdx.x;
        const float4_t v = ((const float4_t*)x)[i];
        half4 hh;
#pragma unroll
        for (int j = 0; j < 4; ++j) hh[j] = (_Float16)v[j];
        ((half4*)xh)[i] = hh;
        return;
    }
    __shared__ float t[64][65];
    const float* in;
    _Float16* out;
    int R, C, bx, by;
    if (bid < 4096 + 768) {
        const int idx = bid - 4096;
        bx = idx % 48; by = idx / 48;
        in = Wqkv; out = WTh; R = 1024; C = 3072;
    } else {
        const int idx = bid - 4864;
        bx = idx & 15; by = idx >> 4;
        in = Wp; out = WpT; R = 1024; C = 1024;
    }
    const int r0 = by * 64, c0 = bx * 64;
    for (int i = threadIdx.x; i < 64 * 64; i += 256) {
        int r = i >> 6, c = i & 63;
        t[r][c] = in[(size_t)(r0 + r) * C + c0 + c];
    }
    __syncthreads();
    for (int i = threadIdx.x; i < 64 * 64; i += 256) {
        int c = i >> 6, r = i & 63;
        out[(size_t)(c0 + c) * R + r0 + r] = (_Float16)t[r][c];
    }
}

// ---------------------------------------------------------------------------
// QKV GEMM, plain fp16, m97 structure: 128x128 tile, BK=32, global_load_lds.
// XCD-bijective block swizzle (T1): 768 = 96/XCD, contiguous tile spans.
// NEW this round: LDS-STAGED COALESCED EPILOGUE. Old epilogue issued 64
// scalar 2B stores/thread (q/k: 32B segments at 4KB stride; V^T: half4 at
// 8KB stride) — store-issue serial + line-granular amplification. Now the
// 128x128 output tile is staged in Tq[128][136] (pad 136: rows 272B = 16B
// aligned, bank-spread) — ROW-major for q/k blocks, COL-major for V blocks
// (col0 is block-uniform; 1024/2048 boundaries are multiples of 128, so
// plane & scale are block-uniform) — then written with 16-lanes-per-256B
// perfectly coalesced half8 stores. LDS 50KB -> still 3 blocks/CU (= grid
// residency 768/256), no occupancy loss.
// Epilogue planes: cols<1024 -> q; 1024..2047 -> k SCALED by log2(e);
// cols>=2048 -> fp16 V^T [1024,4096].
// ---------------------------------------------------------------------------
__global__ __launch_bounds__(256) void gemm_qkv(
    const _Float16* __restrict__ Ag, const _Float16* __restrict__ Bg,
    const float* __restrict__ bias,
    _Float16* __restrict__ qk, _Float16* __restrict__ vt, int K)
{
    constexpr int BK = 32;
    __shared__ _Float16 Ah[128 * BK];
    __shared__ _Float16 Bh[128 * BK];
    __shared__ __align__(16) _Float16 Tq[128][136];   // epilogue staging

    const int tid = threadIdx.x;
    const int wave = tid >> 6, lane = tid & 63;
    const int l16 = lane & 15, quad = lane >> 4;
    const int wr = wave >> 1, wc = wave & 1;
    const int lid = blockIdx.y * 24 + blockIdx.x;      // 0..767
    const int swz = (lid & 7) * 96 + (lid >> 3);       // bijective (768%8==0)
    const int row0 = (swz / 24) * 128, col0 = (swz % 24) * 128;
    const int lrow = lane >> 2, lc8 = (lane & 3) * 8;

    float4_t acc[4][4];
#pragma unroll
    for (int i = 0; i < 4; ++i)
#pragma unroll
        for (int j = 0; j < 4; ++j) acc[i][j] = (float4_t){0.f, 0.f, 0.f, 0.f};

    for (int k0 = 0; k0 < K; k0 += BK) {
        __syncthreads();
#pragma unroll
        for (int i = 0; i < 2; ++i) {
            const int ar = i * 64 + wave * 16;
            __builtin_amdgcn_global_load_lds(
                GLOBAL_AS(Ag + (size_t)(row0 + ar + lrow) * K + k0 + lc8),
                LDS_AS(&Ah[ar * BK]), 16, 0, 0);
            __builtin_amdgcn_global_load_lds(
                GLOBAL_AS(Bg + (size_t)(col0 + ar + lrow) * K + k0 + lc8),
                LDS_AS(&Bh[ar * BK]), 16, 0, 0);
        }
        __syncthreads();

        half8 af[4], bfr[4];
#pragma unroll
        for (int t = 0; t < 4; ++t) {
            af[t]  = *(const half8*)&Ah[(wr * 64 + t * 16 + l16) * BK + quad * 8];
            bfr[t] = *(const half8*)&Bh[(wc * 64 + t * 16 + l16) * BK + quad * 8];
        }
#pragma unroll
        for (int i = 0; i < 4; ++i)
#pragma unroll
            for (int j = 0; j < 4; ++j)
                acc[i][j] = __builtin_amdgcn_mfma_f32_16x16x32_f16(af[i], bfr[j], acc[i][j], 0, 0, 0);
    }

    // ---- epilogue: stage tile in LDS, then coalesced half8 stores ---------
    const bool  isV = (col0 >= 2048);
    const float sc  = (col0 >= 1024 && col0 < 2048) ? LOG2E : 1.0f;
#pragma unroll
    for (int i = 0; i < 4; ++i) {
#pragma unroll
        for (int j = 0; j < 4; ++j) {
            const int col = wc * 64 + j * 16 + l16;
            const float bv = bias[col0 + col];
            const int row = wr * 64 + i * 16 + quad * 4;
            if (isV) {
#pragma unroll
                for (int r = 0; r < 4; ++r)
                    Tq[col][row + r] = (_Float16)(acc[i][j][r] + bv);
            } else {
#pragma unroll
                for (int r = 0; r < 4; ++r)
                    Tq[row + r][col] = (_Float16)((acc[i][j][r] + bv) * sc);
            }
        }
    }
    __syncthreads();
    if (isV) {
        _Float16* base = vt + (size_t)(col0 - 2048) * 4096 + row0;
#pragma unroll
        for (int pass = 0; pass < 8; ++pass) {
            const int c  = pass * 16 + (tid >> 4);
            const int ch = (tid & 15) * 8;
            *(half8*)&base[(size_t)c * 4096 + ch] = *(const half8*)&Tq[c][ch];
        }
    } else {
        _Float16* base = qk + (size_t)row0 * 2048 + col0;
#pragma unroll
        for (int pass = 0; pass < 8; ++pass) {
            const int r  = pass * 16 + (tid >> 4);
            const int ch = (tid & 15) * 8;
            *(half8*)&base[(size_t)r * 2048 + ch] = *(const half8*)&Tq[r][ch];
        }
    }
}

// ---------------------------------------------------------------------------
// Out-projection GEMM, fp16, 128(M)x64(N) tile -> 512 blocks (2/CU).
// XCD-bijective swizzle (512%8==0). C writes are already 64B-coalesced
// (16 lanes x 4B consecutive) — no staging needed.
// ---------------------------------------------------------------------------
__global__ __launch_bounds__(256) void gemm_out(
    const _Float16* __restrict__ Ag, const _Float16* __restrict__ Bg,
    const float* __restrict__ bias, float* __restrict__ C, int N, int K)
{
    constexpr int BK = 32;
    __shared__ _Float16 Ah[128 * BK];
    __shared__ _Float16 Bh[64 * BK];

    const int tid = threadIdx.x;
    const int wave = tid >> 6, lane = tid & 63;
    const int l16 = lane & 15, quad = lane >> 4;
    const int lid = blockIdx.y * 16 + blockIdx.x;      // 0..511
    const int swz = (lid & 7) * 64 + (lid >> 3);       // bijective (512%8==0)
    const int row0 = (swz / 16) * 128, col0 = (swz % 16) * 64;
    const int lrow = lane >> 2, lc8 = (lane & 3) * 8;

    float4_t acc[2][4];
#pragma unroll
    for (int i = 0; i < 2; ++i)
#pragma unroll
        for (int j = 0; j < 4; ++j) acc[i][j] = (float4_t){0.f, 0.f, 0.f, 0.f};

    for (int k0 = 0; k0 < K; k0 += BK) {
        __syncthreads();
#pragma unroll
        for (int i = 0; i < 2; ++i) {
            const int ar = i * 64 + wave * 16;
            __builtin_amdgcn_global_load_lds(
                GLOBAL_AS(Ag + (size_t)(row0 + ar + lrow) * K + k0 + lc8),
                LDS_AS(&Ah[ar * BK]), 16, 0, 0);
        }
        {
            const int br = wave * 16;
            __builtin_amdgcn_global_load_lds(
                GLOBAL_AS(Bg + (size_t)(col0 + br + lrow) * K + k0 + lc8),
                LDS_AS(&Bh[br * BK]), 16, 0, 0);
        }
        __syncthreads();

        half8 af[2], bfr[4];
#pragma unroll
        for (int t = 0; t < 2; ++t)
            af[t] = *(const half8*)&Ah[(wave * 32 + t * 16 + l16) * BK + quad * 8];
#pragma unroll
        for (int t = 0; t < 4; ++t)
            bfr[t] = *(const half8*)&Bh[(t * 16 + l16) * BK + quad * 8];
#pragma unroll
        for (int i = 0; i < 2; ++i)
#pragma unroll
            for (int j = 0; j < 4; ++j)
                acc[i][j] = __builtin_amdgcn_mfma_f32_16x16x32_f16(af[i], bfr[j], acc[i][j], 0, 0, 0);
    }

#pragma unroll
    for (int i = 0; i < 2; ++i) {
#pragma unroll
        for (int j = 0; j < 4; ++j) {
            const int colb = col0 + j * 16 + l16;
            const float bv = bias[colb];
#pragma unroll
            for (int r = 0; r < 4; ++r) {
                const int row = row0 + wave * 32 + i * 16 + quad * 4 + r;
                C[(size_t)row * N + colb] = acc[i][j][r] + bv;
            }
        }
    }
}

// ---------------------------------------------------------------------------
// MFMA causal flash attention — ROUND-6 SCHEDULE RESTORED (best: 66.9us).
// Round-11 post-mortem: KVBLK=128 staging regressed (83.5us): 64KB LDS
// halved resident blocks (occ 25->15.5%); barrier-drain was already hidden
// by co-resident blocks. Five experiments (R7-R11) bracket round-6 as a
// local optimum for the schedule — frozen here. Only retained change vs
// round 6: TREE-reduced softmax max & lsum (depth ~6 vs 31-serial dep
// chain; fp max/add are not compiler-reassociated; ~100cy/iter off the
// critical path; no structural change).
// Structure: 2-way split-K (split s = k-tiles s, s+2, ..., stride 128),
// quartet CU-pairing {(j,s0),(31-j,s0),(j,s1),(31-j,s1)} (66 iters/CU),
// 1024 blocks x 4 waves, 32KB LDS, 64x64 K/V tiles DMA-staged into
// double-buffered XOR-swizzled LDS (slot(row,col8)=row*8+(col8^(row&7))),
// ONE __syncthreads per k-iter, S^T=K Q^T log2-domain 32x32 MFMA,
// cvt_pkrtz+permlane32_swap P-exchange, defer-max (T13), setprio (T5),
// XCD-pinned heads h=(bid&7)*2+((bid>>3)&1); unnormalized partials+(m,l),
// 2-slot combine.
// ---------------------------------------------------------------------------
__global__ __launch_bounds__(256, 4) void flash_attn_f16(
    const _Float16* __restrict__ qk, const _Float16* __restrict__ v_t,
    _Float16* __restrict__ opart, float* __restrict__ mlpart)
{
    __shared__ __align__(16) _Float16 KsT[2][64 * 64];   // [buf][slot*8]
    __shared__ __align__(16) _Float16 VtT[2][64 * 64];

    const int bid  = blockIdx.x;
    const int g    = bid & 255;                 // residency group (CU)
    const int hv   = g & 15;
    const int h    = (hv & 7) * 2 + (hv >> 3);  // XCD-pinned heads
    const int j    = g >> 4;                    // 0..15
    const int v    = bid >> 8;                  // 0..3
    const int tile = (v & 1) ? (31 - j) : j;    // quartet sums to 66 iters
    const int split= v >> 1;                    // 0: even k-tiles, 1: odd

    const int wave = threadIdx.x >> 6;          // 0..3
    const int lane = threadIdx.x & 63;
    const int l31  = lane & 31;
    const int hi   = lane >> 5;                 // 0/1

    // DMA source-address components (lane's LDS slot is wave*128+p*64+lane):
    const int dma_r = wave * 16 + (lane >> 3);             // row  (+ p*8)
    const int dma_c = ((lane & 7) ^ (lane >> 3)) * 8;      // logical col (halfs)

    const _Float16* kplane = qk + 1024 + h * HDIM;
    const _Float16* vplane = v_t + (size_t)h * HDIM * 4096;

    const int q0 = tile * 128 + wave * 32;

    // ---- Q fragment (B-operand of 32x32x16): col=q=l31, k=16j+8*hi ------
    half8 qf[4];
#pragma unroll
    for (int jj = 0; jj < 4; ++jj)
        qf[jj] = *(const half8*)(qk + (size_t)(q0 + l31) * 2048 + h * HDIM
                                 + jj * 16 + hi * 8);

    float16_t o0 = (float16_t)0.f, o1 = (float16_t)0.f;
    float m_r = -INFINITY, l_r = 0.f;

    // ---- pre-stage first k-tile (kb = 64*split) into buf 0 ----------------
    const int kb0 = 64 * split;
#pragma unroll
    for (int p = 0; p < 2; ++p) {
        const int r = dma_r + p * 8;
        __builtin_amdgcn_global_load_lds(
            GLOBAL_AS(kplane + (size_t)(kb0 + r) * 2048 + dma_c),
            LDS_AS(&KsT[0][(wave * 128 + p * 64) * 8]), 16, 0, 0);
        __builtin_amdgcn_global_load_lds(
            GLOBAL_AS(vplane + (size_t)r * 4096 + kb0 + dma_c),
            LDS_AS(&VtT[0][(wave * 128 + p * 64) * 8]), 16, 0, 0);
    }

    int ib = 0;
    int kb = kb0;
    for (int it = 0; it <= tile; ++it, kb += 128, ib ^= 1) {
        __syncthreads();   // DMA(buf ib) done (vmcnt drain) + readers done

        if (it < tile) {   // async DMA of next tile (stride 128) into buf^1
            const int kn = kb + 128;
#pragma unroll
            for (int p = 0; p < 2; ++p) {
                const int r = dma_r + p * 8;
                __builtin_amdgcn_global_load_lds(
                    GLOBAL_AS(kplane + (size_t)(kn + r) * 2048 + dma_c),
                    LDS_AS(&KsT[ib ^ 1][(wave * 128 + p * 64) * 8]), 16, 0, 0);
                __builtin_amdgcn_global_load_lds(
                    GLOBAL_AS(vplane + (size_t)r * 4096 + kn + dma_c),
                    LDS_AS(&VtT[ib ^ 1][(wave * 128 + p * 64) * 8]), 16, 0, 0);
            }
        }

        // fully-masked trailing tile (split 1, waves 0/1): skip compute
        if (kb <= q0 + 31) {
            // ---- S^T = K Q^T (log2-domain logits), 2 key-chunks ----------
            float16_t s0 = (float16_t)0.f, s1 = (float16_t)0.f;
            __builtin_amdgcn_s_setprio(1);
#pragma unroll
            for (int jj = 0; jj < 4; ++jj) {
                const int r7 = l31 & 7;
                const half8 kf0 = *(const half8*)&KsT[ib][
                    ((l31) * 8 + ((2 * jj + hi) ^ r7)) * 8];
                const half8 kf1 = *(const half8*)&KsT[ib][
                    ((32 + l31) * 8 + ((2 * jj + hi) ^ r7)) * 8];
                s0 = __builtin_amdgcn_mfma_f32_32x32x16_f16(kf0, qf[jj], s0, 0, 0, 0);
                s1 = __builtin_amdgcn_mfma_f32_32x32x16_f16(kf1, qf[jj], s1, 0, 0, 0);
            }
            __builtin_amdgcn_s_setprio(0);

            // ---- causal mask (diagonal-straddling tile only) --------------
            if (kb + 63 > q0) {
                const int qg = q0 + l31;
#pragma unroll
                for (int gg = 0; gg < 4; ++gg)
#pragma unroll
                    for (int r = 0; r < 4; ++r) {
                        const int keyb = kb + r + 8 * gg + 4 * hi;
                        if (keyb > qg)      s0[4 * gg + r] = -INFINITY;
                        if (keyb + 32 > qg) s1[4 * gg + r] = -INFINITY;
                    }
            }

            // ---- online softmax: TREE max (depth ~6) + ONE shfl, T13 ------
            float a0 = fmaxf(s0[0], s0[1]),  a1 = fmaxf(s0[2], s0[3]);
            float a2 = fmaxf(s0[4], s0[5]),  a3 = fmaxf(s0[6], s0[7]);
            float a4 = fmaxf(s0[8], s0[9]),  a5 = fmaxf(s0[10], s0[11]);
            float a6 = fmaxf(s0[12], s0[13]), a7 = fmaxf(s0[14], s0[15]);
            float b0 = fmaxf(s1[0], s1[1]),  b1 = fmaxf(s1[2], s1[3]);
            float b2 = fmaxf(s1[4], s1[5]),  b3 = fmaxf(s1[6], s1[7]);
            float b4 = fmaxf(s1[8], s1[9]),  b5 = fmaxf(s1[10], s1[11]);
            float b6 = fmaxf(s1[12], s1[13]), b7 = fmaxf(s1[14], s1[15]);
            a0 = fmaxf(a0, a1); a2 = fmaxf(a2, a3);
            a4 = fmaxf(a4, a5); a6 = fmaxf(a6, a7);
            b0 = fmaxf(b0, b1); b2 = fmaxf(b2, b3);
            b4 = fmaxf(b4, b5); b6 = fmaxf(b6, b7);
            a0 = fmaxf(a0, a2); a4 = fmaxf(a4, a6);
            b0 = fmaxf(b0, b2); b4 = fmaxf(b4, b6);
            float mx = fmaxf(fmaxf(a0, a4), fmaxf(b0, b4));
            mx = fmaxf(mx, __shfl_xor(mx, 32));
            const bool  grow  = mx > m_r + 8.0f;
            const float mnew  = grow ? mx : m_r;
            const float alpha = __builtin_amdgcn_exp2f(m_r - mnew); // 1 if !grow

            // ---- P = exp2(S - m), pack to fp16 words; tree lsum -----------
            int w0[8], w1[8];
            float ls0 = 0.f, ls1 = 0.f, ls2 = 0.f, ls3 = 0.f;
#pragma unroll
            for (int i = 0; i < 8; ++i) {
                const float pa = __builtin_amdgcn_exp2f(s0[2 * i]     - mnew);
                const float pb = __builtin_amdgcn_exp2f(s0[2 * i + 1] - mnew);
                if (i & 1) ls1 += pa + pb; else ls0 += pa + pb;
                w0[i] = __builtin_bit_cast(int, __builtin_amdgcn_cvt_pkrtz(pa, pb));
            }
#pragma unroll
            for (int i = 0; i < 8; ++i) {
                const float pa = __builtin_amdgcn_exp2f(s1[2 * i]     - mnew);
                const float pb = __builtin_amdgcn_exp2f(s1[2 * i + 1] - mnew);
                if (i & 1) ls3 += pa + pb; else ls2 += pa + pb;
                w1[i] = __builtin_bit_cast(int, __builtin_amdgcn_cvt_pkrtz(pa, pb));
            }
            const float lsum = (ls0 + ls1) + (ls2 + ls3);
            l_r = l_r * alpha + lsum;  // per-lane partial (alpha row-uniform)
            m_r = mnew;
            if (__any(grow)) {
#pragma unroll
                for (int i = 0; i < 16; ++i) { o0[i] *= alpha; o1[i] *= alpha; }
            }

            // ---- P -> B-operand frags via permlane32_swap (no LDS) --------
            half8 pf[4];
            {
                const int2_t c02 = __builtin_amdgcn_permlane32_swap(w0[0], w0[2], 0, 0);
                const int2_t c13 = __builtin_amdgcn_permlane32_swap(w0[1], w0[3], 0, 0);
                const int2_t c46 = __builtin_amdgcn_permlane32_swap(w0[4], w0[6], 0, 0);
                const int2_t c57 = __builtin_amdgcn_permlane32_swap(w0[5], w0[7], 0, 0);
                int4_t f0 = {c02[0], c13[0], c02[1], c13[1]};
                int4_t f1 = {c46[0], c57[0], c46[1], c57[1]};
                pf[0] = __builtin_bit_cast(half8, f0);
                pf[1] = __builtin_bit_cast(half8, f1);
                const int2_t d02 = __builtin_amdgcn_permlane32_swap(w1[0], w1[2], 0, 0);
                const int2_t d13 = __builtin_amdgcn_permlane32_swap(w1[1], w1[3], 0, 0);
                const int2_t d46 = __builtin_amdgcn_permlane32_swap(w1[4], w1[6], 0, 0);
                const int2_t d57 = __builtin_amdgcn_permlane32_swap(w1[5], w1[7], 0, 0);
                int4_t f2 = {d02[0], d13[0], d02[1], d13[1]};
                int4_t f3 = {d46[0], d57[0], d46[1], d57[1]};
                pf[2] = __builtin_bit_cast(half8, f2);
                pf[3] = __builtin_bit_cast(half8, f3);
            }

            // ---- O^T += V^T P^T -------------------------------------------
            __builtin_amdgcn_s_setprio(1);
#pragma unroll
            for (int kc = 0; kc < 4; ++kc) {
                const int r7 = l31 & 7;
                const half8 vf0 = *(const half8*)&VtT[ib][
                    ((l31) * 8 + ((2 * kc + hi) ^ r7)) * 8];
                const half8 vf1 = *(const half8*)&VtT[ib][
                    ((32 + l31) * 8 + ((2 * kc + hi) ^ r7)) * 8];
                o0 = __builtin_amdgcn_mfma_f32_32x32x16_f16(vf0, pf[kc], o0, 0, 0, 0);
                o1 = __builtin_amdgcn_mfma_f32_32x32x16_f16(vf1, pf[kc], o1, 0, 0, 0);
            }
            __builtin_amdgcn_s_setprio(0);
        } // active
    } // kb

    // ---- epilogue: store UNNORMALIZED partials + (m, l) -------------------
    const float lr = l_r + __shfl_xor(l_r, 32);
    const size_t prow = (size_t)(split * 4096 + q0 + l31);
#pragma unroll
    for (int gg = 0; gg < 4; ++gg) {
        half4 wa, wb;
#pragma unroll
        for (int r = 0; r < 4; ++r) {
            wa[r] = (_Float16)o0[4 * gg + r];
            wb[r] = (_Float16)o1[4 * gg + r];
        }
        const size_t base = prow * 1024 + h * HDIM + 8 * gg + 4 * hi;
        *(half4*)&opart[base]      = wa;
        *(half4*)&opart[base + 32] = wb;
    }
    if (hi == 0) {
        float2 ml; ml.x = m_r; ml.y = lr;
        ((float2*)mlpart)[prow * 16 + h] = ml;
    }
}

// ---------------------------------------------------------------------------
// combine: merge the two split-K partials per (row, head); write resh fp16.
// 524288 threads, one half8 of d-values each. ~25 MB traffic, ~6 us.
// ---------------------------------------------------------------------------
__global__ __launch_bounds__(256) void combine(
    const _Float16* __restrict__ opart, const float* __restrict__ mlpart,
    _Float16* __restrict__ resh)
{
    const int idx = blockIdx.x * 256 + threadIdx.x;   // 0..524287
    const int row = idx >> 7;                          // 0..4095
    const int c8  = (idx & 127) * 8;                   // d-offset in the row
    const int h   = c8 >> 6;
    const float2 ml0 = ((const float2*)mlpart)[(size_t)row * 16 + h];
    const float2 ml1 = ((const float2*)mlpart)[(size_t)(4096 + row) * 16 + h];
    const float m  = fmaxf(ml0.x, ml1.x);              // m0 always finite
    const float a0 = __builtin_amdgcn_exp2f(ml0.x - m);
    const float a1 = __builtin_amdgcn_exp2f(ml1.x - m);  // 0 if m1 = -inf
    const float inv = 1.0f / (ml0.y * a0 + ml1.y * a1);  // l0 > 0 always
    const half8 o0 = *(const half8*)&opart[(size_t)row * 1024 + c8];
    const half8 o1 = *(const half8*)&opart[(size_t)(4096 + row) * 1024 + c8];
    half8 w;
#pragma unroll
    for (int jj = 0; jj < 8; ++jj)
        w[jj] = (_Float16)(((float)o0[jj] * a0 + (float)o1[jj] * a1) * inv);
    *(half8*)&resh[(size_t)row * 1024 + c8] = w;
}

// ---------------------------------------------------------------------------
// launch
// ---------------------------------------------------------------------------
extern "C" void kernel_launch(void* const* d_in, const int* in_sizes, int n_in,
                              void* d_out, int out_size, void* d_ws, size_t ws_size,
                              hipStream_t stream)
{
    const float* x    = (const float*)d_in[0];
    const float* Wqkv = (const float*)d_in[2];
    const float* bqkv = (const float*)d_in[3];
    const float* Wp   = (const float*)d_in[4];
    const float* bp   = (const float*)d_in[5];
    float* out = (float*)d_out;

    _Float16* xh  = (_Float16*)d_ws;                 // [4096,1024] fp16  8MB
    _Float16* WTh = xh + (size_t)4096 * 1024;        // [3072,1024] fp16  6MB
    _Float16* qkh = WTh + (size_t)3072 * 1024;       // [4096,2048] fp16 16MB
    _Float16* vtg = qkh + (size_t)4096 * 2048;       // V^T [1024,4096]   8MB
    _Float16* WpT = vtg + (size_t)1024 * 4096;       // [1024,1024] fp16  2MB
    _Float16* opart = WpT + (size_t)1024 * 1024;     // [2,4096,1024] fp16 16MB
    float* mlpart = (float*)(opart + (size_t)2 * 4096 * 1024);  // [2,4096,16,2] f32 1MB
    _Float16* resh = xh;            // alias: x fp16 dead after QKV GEMM

    dim3 blk(256);

    prep<<<dim3(5120), blk, 0, stream>>>(x, Wqkv, Wp, xh, WTh, WpT);

    gemm_qkv<<<dim3(3072 / 128, 4096 / 128), blk, 0, stream>>>(
        xh, WTh, bqkv, qkh, vtg, 1024);

    flash_attn_f16<<<dim3(1024), dim3(256), 0, stream>>>(qkh, vtg, opart, mlpart);

    combine<<<dim3(2048), blk, 0, stream>>>(opart, mlpart, resh);

    gemm_out<<<dim3(1024 / 64, 4096 / 128), blk, 0, stream>>>(
        resh, WpT, bp, out, 1024, 1024);
}

// Round 13
// 234.799 us; speedup vs baseline: 1.0761x; 1.0404x over previous
//
#include <hip/hip_runtime.h>
#include <hip/hip_bf16.h>
#include <math.h>

#define S_LEN 4096
#define EMB   1024
#define NHEAD 16
#define HDIM  64

typedef __attribute__((ext_vector_type(8))) _Float16 half8;
typedef __attribute__((ext_vector_type(4))) _Float16 half4;
typedef __attribute__((ext_vector_type(4))) float float4_t;
typedef __attribute__((ext_vector_type(16))) float float16_t;
typedef __attribute__((ext_vector_type(4))) int int4_t;
typedef __attribute__((ext_vector_type(2))) int int2_t;

#define GLOBAL_AS(p) ((const __attribute__((address_space(1))) void*)(p))
#define LDS_AS(p)    ((__attribute__((address_space(3))) void*)(p))

#define LOG2E 1.4426950408889634f

// ---------------------------------------------------------------------------
// fused prep: blocks [0,4096) convert x fp32->fp16; [4096,4864) transpose
// Wqkv [1024,3072] -> WTh [3072,1024]; [4864,5120) transpose Wp -> WpT.
// ---------------------------------------------------------------------------
__global__ __launch_bounds__(256) void prep(
    const float* __restrict__ x, const float* __restrict__ Wqkv,
    const float* __restrict__ Wp,
    _Float16* __restrict__ xh, _Float16* __restrict__ WTh,
    _Float16* __restrict__ WpT)
{
    const int bid = blockIdx.x;
    if (bid < 4096) {
        const int i = bid * 256 + threadIdx.x;
        const float4_t v = ((const float4_t*)x)[i];
        half4 hh;
#pragma unroll
        for (int j = 0; j < 4; ++j) hh[j] = (_Float16)v[j];
        ((half4*)xh)[i] = hh;
        return;
    }
    __shared__ float t[64][65];
    const float* in;
    _Float16* out;
    int R, C, bx, by;
    if (bid < 4096 + 768) {
        const int idx = bid - 4096;
        bx = idx % 48; by = idx / 48;
        in = Wqkv; out = WTh; R = 1024; C = 3072;
    } else {
        const int idx = bid - 4864;
        bx = idx & 15; by = idx >> 4;
        in = Wp; out = WpT; R = 1024; C = 1024;
    }
    const int r0 = by * 64, c0 = bx * 64;
    for (int i = threadIdx.x; i < 64 * 64; i += 256) {
        int r = i >> 6, c = i & 63;
        t[r][c] = in[(size_t)(r0 + r) * C + c0 + c];
    }
    __syncthreads();
    for (int i = threadIdx.x; i < 64 * 64; i += 256) {
        int c = i >> 6, r = i & 63;
        out[(size_t)(c0 + c) * R + r0 + r] = (_Float16)t[r][c];
    }
}

// ---------------------------------------------------------------------------
// QKV GEMM, fp16, 128x128 tile — THIS ROUND: BK=64 (half the barriers; m233:
// 2-phase cost is ~72% stage+vmcnt+barrier, so fewer barrier events is the
// lever at short K). Supports:
//  - XOR source-permuted staging (flash-proven): LDS slot(row,chunk8) =
//    row*64 + (chunk ^ (row&7))*8, DMA dest linear, fragment reads swizzled
//    -> ~2-way banks (BK=64 rows are 128B-strided = 16-way if linear).
//  - Tq epilogue buffer UNIONED with Ah/Bh (both 32KB vs Tq 34.8KB) -> LDS
//    34.8KB, still 3 blocks/CU (= grid 768/256). Barrier before Tq fill.
//  - 2D XCD swizzle: 96 blocks/XCD as 8 rows x 12 cols (footprint 5MB vs
//    7MB for the 4MB per-XCD L2).
// Epilogue planes: cols<1024 -> q; 1024..2047 -> k SCALED by log2(e);
// cols>=2048 -> fp16 V^T [1024,4096]. Coalesced half8 stores via Tq.
// ---------------------------------------------------------------------------
__global__ __launch_bounds__(256) void gemm_qkv(
    const _Float16* __restrict__ Ag, const _Float16* __restrict__ Bg,
    const float* __restrict__ bias,
    _Float16* __restrict__ qk, _Float16* __restrict__ vt, int K)
{
    constexpr int BK = 64;
    __shared__ __align__(16) _Float16 smem[128 * 136];   // union buffer
    _Float16* Ah = smem;                // [128][64]
    _Float16* Bh = smem + 128 * 64;     // [128][64]
    auto Tq = (_Float16(*)[136])smem;   // epilogue staging (aliases Ah/Bh)

    const int tid = threadIdx.x;
    const int wave = tid >> 6, lane = tid & 63;
    const int l16 = lane & 15, quad = lane >> 4;
    const int wr = wave >> 1, wc = wave & 1;
    const int lid = blockIdx.y * 24 + blockIdx.x;      // 0..767
    const int xcd = lid & 7, idx = lid >> 3;           // 2D XCD swizzle
    const int row0 = ((xcd >> 1) * 8 + (idx & 7)) * 128;
    const int col0 = ((xcd & 1) * 12 + (idx >> 3)) * 128;
    const int srow = lane >> 3;                        // staging row in 8-group
    const int sc8  = ((lane & 7) ^ (srow & 7)) * 8;    // XOR-permuted source col

    float4_t acc[4][4];
#pragma unroll
    for (int i = 0; i < 4; ++i)
#pragma unroll
        for (int j = 0; j < 4; ++j) acc[i][j] = (float4_t){0.f, 0.f, 0.f, 0.f};

    for (int k0 = 0; k0 < K; k0 += BK) {
        __syncthreads();
#pragma unroll
        for (int i = 0; i < 4; ++i) {
            const int ar = i * 32 + wave * 8;          // 8 rows per wave-issue
            __builtin_amdgcn_global_load_lds(
                GLOBAL_AS(Ag + (size_t)(row0 + ar + srow) * K + k0 + sc8),
                LDS_AS(&Ah[ar * 64]), 16, 0, 0);
            __builtin_amdgcn_global_load_lds(
                GLOBAL_AS(Bg + (size_t)(col0 + ar + srow) * K + k0 + sc8),
                LDS_AS(&Bh[ar * 64]), 16, 0, 0);
        }
        __syncthreads();

        half8 af[4][2], bfr[4][2];
#pragma unroll
        for (int t = 0; t < 4; ++t) {
#pragma unroll
            for (int ks = 0; ks < 2; ++ks) {
                const int ra = wr * 64 + t * 16 + l16;
                const int rb = wc * 64 + t * 16 + l16;
                const int cc = ks * 4 + quad;
                af[t][ks]  = *(const half8*)&Ah[ra * 64 + ((cc ^ (ra & 7))) * 8];
                bfr[t][ks] = *(const half8*)&Bh[rb * 64 + ((cc ^ (rb & 7))) * 8];
            }
        }
#pragma unroll
        for (int ks = 0; ks < 2; ++ks)
#pragma unroll
            for (int i = 0; i < 4; ++i)
#pragma unroll
                for (int j = 0; j < 4; ++j)
                    acc[i][j] = __builtin_amdgcn_mfma_f32_16x16x32_f16(
                        af[i][ks], bfr[j][ks], acc[i][j], 0, 0, 0);
    }

    // ---- epilogue: stage tile in LDS (aliases Ah/Bh!), coalesced stores ---
    __syncthreads();   // all Ah/Bh reads done before Tq overwrites
    const bool  isV = (col0 >= 2048);
    const float sc  = (col0 >= 1024 && col0 < 2048) ? LOG2E : 1.0f;
#pragma unroll
    for (int i = 0; i < 4; ++i) {
#pragma unroll
        for (int j = 0; j < 4; ++j) {
            const int col = wc * 64 + j * 16 + l16;
            const float bv = bias[col0 + col];
            const int row = wr * 64 + i * 16 + quad * 4;
            if (isV) {
#pragma unroll
                for (int r = 0; r < 4; ++r)
                    Tq[col][row + r] = (_Float16)(acc[i][j][r] + bv);
            } else {
#pragma unroll
                for (int r = 0; r < 4; ++r)
                    Tq[row + r][col] = (_Float16)((acc[i][j][r] + bv) * sc);
            }
        }
    }
    __syncthreads();
    if (isV) {
        _Float16* base = vt + (size_t)(col0 - 2048) * 4096 + row0;
#pragma unroll
        for (int pass = 0; pass < 8; ++pass) {
            const int c  = pass * 16 + (tid >> 4);
            const int ch = (tid & 15) * 8;
            *(half8*)&base[(size_t)c * 4096 + ch] = *(const half8*)&Tq[c][ch];
        }
    } else {
        _Float16* base = qk + (size_t)row0 * 2048 + col0;
#pragma unroll
        for (int pass = 0; pass < 8; ++pass) {
            const int r  = pass * 16 + (tid >> 4);
            const int ch = (tid & 15) * 8;
            *(half8*)&base[(size_t)r * 2048 + ch] = *(const half8*)&Tq[r][ch];
        }
    }
}

// ---------------------------------------------------------------------------
// Out-projection GEMM, fp16, 128(M)x64(N) tile -> 512 blocks (2/CU).
// THIS ROUND: BK=64 (half the barriers) + XOR source-permuted staging
// (same scheme as gemm_qkv). LDS 24KB. XCD-bijective swizzle (512%8==0).
// C writes already 64B-coalesced.
// ---------------------------------------------------------------------------
__global__ __launch_bounds__(256) void gemm_out(
    const _Float16* __restrict__ Ag, const _Float16* __restrict__ Bg,
    const float* __restrict__ bias, float* __restrict__ C, int N, int K)
{
    constexpr int BK = 64;
    __shared__ __align__(16) _Float16 Ah[128 * 64];
    __shared__ __align__(16) _Float16 Bh[64 * 64];

    const int tid = threadIdx.x;
    const int wave = tid >> 6, lane = tid & 63;
    const int l16 = lane & 15, quad = lane >> 4;
    const int lid = blockIdx.y * 16 + blockIdx.x;      // 0..511
    const int swz = (lid & 7) * 64 + (lid >> 3);       // bijective (512%8==0)
    const int row0 = (swz / 16) * 128, col0 = (swz % 16) * 64;
    const int srow = lane >> 3;
    const int sc8  = ((lane & 7) ^ (srow & 7)) * 8;

    float4_t acc[2][4];
#pragma unroll
    for (int i = 0; i < 2; ++i)
#pragma unroll
        for (int j = 0; j < 4; ++j) acc[i][j] = (float4_t){0.f, 0.f, 0.f, 0.f};

    for (int k0 = 0; k0 < K; k0 += BK) {
        __syncthreads();
#pragma unroll
        for (int i = 0; i < 4; ++i) {
            const int ar = i * 32 + wave * 8;
            __builtin_amdgcn_global_load_lds(
                GLOBAL_AS(Ag + (size_t)(row0 + ar + srow) * K + k0 + sc8),
                LDS_AS(&Ah[ar * 64]), 16, 0, 0);
        }
#pragma unroll
        for (int i = 0; i < 2; ++i) {
            const int br = i * 32 + wave * 8;
            __builtin_amdgcn_global_load_lds(
                GLOBAL_AS(Bg + (size_t)(col0 + br + srow) * K + k0 + sc8),
                LDS_AS(&Bh[br * 64]), 16, 0, 0);
        }
        __syncthreads();

        half8 af[2][2], bfr[4][2];
#pragma unroll
        for (int ks = 0; ks < 2; ++ks) {
#pragma unroll
            for (int t = 0; t < 2; ++t) {
                const int ra = wave * 32 + t * 16 + l16;
                const int cc = ks * 4 + quad;
                af[t][ks] = *(const half8*)&Ah[ra * 64 + ((cc ^ (ra & 7))) * 8];
            }
#pragma unroll
            for (int t = 0; t < 4; ++t) {
                const int rb = t * 16 + l16;
                const int cc = ks * 4 + quad;
                bfr[t][ks] = *(const half8*)&Bh[rb * 64 + ((cc ^ (rb & 7))) * 8];
            }
        }
#pragma unroll
        for (int ks = 0; ks < 2; ++ks)
#pragma unroll
            for (int i = 0; i < 2; ++i)
#pragma unroll
                for (int j = 0; j < 4; ++j)
                    acc[i][j] = __builtin_amdgcn_mfma_f32_16x16x32_f16(
                        af[i][ks], bfr[j][ks], acc[i][j], 0, 0, 0);
    }

#pragma unroll
    for (int i = 0; i < 2; ++i) {
#pragma unroll
        for (int j = 0; j < 4; ++j) {
            const int colb = col0 + j * 16 + l16;
            const float bv = bias[colb];
#pragma unroll
            for (int r = 0; r < 4; ++r) {
                const int row = row0 + wave * 32 + i * 16 + quad * 4 + r;
                C[(size_t)row * N + colb] = acc[i][j][r] + bv;
            }
        }
    }
}

// ---------------------------------------------------------------------------
// MFMA causal flash attention — EXACT ROUND-6 KERNEL (66.9us best).
// Round-12 post-mortem: tree-reduced softmax REGRESSED (70.3us, VGPR 60->64)
// — the serial chain was already hidden under MFMA/wave overlap; reverted.
// Frozen structure (R7-R11 bracketed this as the local optimum):
// 2-way split-K (split s = k-tiles s, s+2, ..., stride 128), quartet
// CU-pairing {(j,s0),(31-j,s0),(j,s1),(31-j,s1)} (66 iters/CU), 1024 blocks
// x 4 waves, 32KB LDS, 64x64 K/V tiles DMA-staged into double-buffered
// XOR-swizzled LDS (slot(row,col8)=row*8+(col8^(row&7))), ONE __syncthreads
// per k-iter, S^T=K Q^T log2-domain 32x32 MFMA, cvt_pkrtz+permlane32_swap
// P-exchange, defer-max (T13), setprio (T5), XCD-pinned heads
// h=(bid&7)*2+((bid>>3)&1); unnormalized partials+(m,l), 2-slot combine.
// ---------------------------------------------------------------------------
__global__ __launch_bounds__(256, 4) void flash_attn_f16(
    const _Float16* __restrict__ qk, const _Float16* __restrict__ v_t,
    _Float16* __restrict__ opart, float* __restrict__ mlpart)
{
    __shared__ __align__(16) _Float16 KsT[2][64 * 64];   // [buf][slot*8]
    __shared__ __align__(16) _Float16 VtT[2][64 * 64];

    const int bid  = blockIdx.x;
    const int g    = bid & 255;                 // residency group (CU)
    const int hv   = g & 15;
    const int h    = (hv & 7) * 2 + (hv >> 3);  // XCD-pinned heads
    const int j    = g >> 4;                    // 0..15
    const int v    = bid >> 8;                  // 0..3
    const int tile = (v & 1) ? (31 - j) : j;    // quartet sums to 66 iters
    const int split= v >> 1;                    // 0: even k-tiles, 1: odd

    const int wave = threadIdx.x >> 6;          // 0..3
    const int lane = threadIdx.x & 63;
    const int l31  = lane & 31;
    const int hi   = lane >> 5;                 // 0/1

    // DMA source-address components (lane's LDS slot is wave*128+p*64+lane):
    const int dma_r = wave * 16 + (lane >> 3);             // row  (+ p*8)
    const int dma_c = ((lane & 7) ^ (lane >> 3)) * 8;      // logical col (halfs)

    const _Float16* kplane = qk + 1024 + h * HDIM;
    const _Float16* vplane = v_t + (size_t)h * HDIM * 4096;

    const int q0 = tile * 128 + wave * 32;

    // ---- Q fragment (B-operand of 32x32x16): col=q=l31, k=16j+8*hi ------
    half8 qf[4];
#pragma unroll
    for (int jj = 0; jj < 4; ++jj)
        qf[jj] = *(const half8*)(qk + (size_t)(q0 + l31) * 2048 + h * HDIM
                                 + jj * 16 + hi * 8);

    float16_t o0 = (float16_t)0.f, o1 = (float16_t)0.f;
    float m_r = -INFINITY, l_r = 0.f;

    // ---- pre-stage first k-tile (kb = 64*split) into buf 0 ----------------
    const int kb0 = 64 * split;
#pragma unroll
    for (int p = 0; p < 2; ++p) {
        const int r = dma_r + p * 8;
        __builtin_amdgcn_global_load_lds(
            GLOBAL_AS(kplane + (size_t)(kb0 + r) * 2048 + dma_c),
            LDS_AS(&KsT[0][(wave * 128 + p * 64) * 8]), 16, 0, 0);
        __builtin_amdgcn_global_load_lds(
            GLOBAL_AS(vplane + (size_t)r * 4096 + kb0 + dma_c),
            LDS_AS(&VtT[0][(wave * 128 + p * 64) * 8]), 16, 0, 0);
    }

    int ib = 0;
    int kb = kb0;
    for (int it = 0; it <= tile; ++it, kb += 128, ib ^= 1) {
        __syncthreads();   // DMA(buf ib) done (vmcnt drain) + readers done

        if (it < tile) {   // async DMA of next tile (stride 128) into buf^1
            const int kn = kb + 128;
#pragma unroll
            for (int p = 0; p < 2; ++p) {
                const int r = dma_r + p * 8;
                __builtin_amdgcn_global_load_lds(
                    GLOBAL_AS(kplane + (size_t)(kn + r) * 2048 + dma_c),
                    LDS_AS(&KsT[ib ^ 1][(wave * 128 + p * 64) * 8]), 16, 0, 0);
                __builtin_amdgcn_global_load_lds(
                    GLOBAL_AS(vplane + (size_t)r * 4096 + kn + dma_c),
                    LDS_AS(&VtT[ib ^ 1][(wave * 128 + p * 64) * 8]), 16, 0, 0);
            }
        }

        // fully-masked trailing tile (split 1, waves 0/1): skip compute
        if (kb <= q0 + 31) {
            // ---- S^T = K Q^T (log2-domain logits), 2 key-chunks ----------
            float16_t s0 = (float16_t)0.f, s1 = (float16_t)0.f;
            __builtin_amdgcn_s_setprio(1);
#pragma unroll
            for (int jj = 0; jj < 4; ++jj) {
                const int r7 = l31 & 7;
                const half8 kf0 = *(const half8*)&KsT[ib][
                    ((l31) * 8 + ((2 * jj + hi) ^ r7)) * 8];
                const half8 kf1 = *(const half8*)&KsT[ib][
                    ((32 + l31) * 8 + ((2 * jj + hi) ^ r7)) * 8];
                s0 = __builtin_amdgcn_mfma_f32_32x32x16_f16(kf0, qf[jj], s0, 0, 0, 0);
                s1 = __builtin_amdgcn_mfma_f32_32x32x16_f16(kf1, qf[jj], s1, 0, 0, 0);
            }
            __builtin_amdgcn_s_setprio(0);

            // ---- causal mask (diagonal-straddling tile only) --------------
            if (kb + 63 > q0) {
                const int qg = q0 + l31;
#pragma unroll
                for (int gg = 0; gg < 4; ++gg)
#pragma unroll
                    for (int r = 0; r < 4; ++r) {
                        const int keyb = kb + r + 8 * gg + 4 * hi;
                        if (keyb > qg)      s0[4 * gg + r] = -INFINITY;
                        if (keyb + 32 > qg) s1[4 * gg + r] = -INFINITY;
                    }
            }

            // ---- online softmax: 31 fmax + ONE shfl, defer-max (T13) ------
            float mx = s0[0];
#pragma unroll
            for (int i = 1; i < 16; ++i) mx = fmaxf(mx, s0[i]);
#pragma unroll
            for (int i = 0; i < 16; ++i) mx = fmaxf(mx, s1[i]);
            mx = fmaxf(mx, __shfl_xor(mx, 32));
            const bool  grow  = mx > m_r + 8.0f;
            const float mnew  = grow ? mx : m_r;
            const float alpha = __builtin_amdgcn_exp2f(m_r - mnew); // 1 if !grow

            // ---- P = exp2(S - m), pack to fp16 words ----------------------
            int w0[8], w1[8];
            float lsum = 0.f;
#pragma unroll
            for (int i = 0; i < 8; ++i) {
                const float pa = __builtin_amdgcn_exp2f(s0[2 * i]     - mnew);
                const float pb = __builtin_amdgcn_exp2f(s0[2 * i + 1] - mnew);
                lsum += pa + pb;
                w0[i] = __builtin_bit_cast(int, __builtin_amdgcn_cvt_pkrtz(pa, pb));
            }
#pragma unroll
            for (int i = 0; i < 8; ++i) {
                const float pa = __builtin_amdgcn_exp2f(s1[2 * i]     - mnew);
                const float pb = __builtin_amdgcn_exp2f(s1[2 * i + 1] - mnew);
                lsum += pa + pb;
                w1[i] = __builtin_bit_cast(int, __builtin_amdgcn_cvt_pkrtz(pa, pb));
            }
            l_r = l_r * alpha + lsum;  // per-lane partial (alpha row-uniform)
            m_r = mnew;
            if (__any(grow)) {
#pragma unroll
                for (int i = 0; i < 16; ++i) { o0[i] *= alpha; o1[i] *= alpha; }
            }

            // ---- P -> B-operand frags via permlane32_swap (no LDS) --------
            half8 pf[4];
            {
                const int2_t a02 = __builtin_amdgcn_permlane32_swap(w0[0], w0[2], 0, 0);
                const int2_t a13 = __builtin_amdgcn_permlane32_swap(w0[1], w0[3], 0, 0);
                const int2_t a46 = __builtin_amdgcn_permlane32_swap(w0[4], w0[6], 0, 0);
                const int2_t a57 = __builtin_amdgcn_permlane32_swap(w0[5], w0[7], 0, 0);
                int4_t f0 = {a02[0], a13[0], a02[1], a13[1]};
                int4_t f1 = {a46[0], a57[0], a46[1], a57[1]};
                pf[0] = __builtin_bit_cast(half8, f0);
                pf[1] = __builtin_bit_cast(half8, f1);
                const int2_t b02 = __builtin_amdgcn_permlane32_swap(w1[0], w1[2], 0, 0);
                const int2_t b13 = __builtin_amdgcn_permlane32_swap(w1[1], w1[3], 0, 0);
                const int2_t b46 = __builtin_amdgcn_permlane32_swap(w1[4], w1[6], 0, 0);
                const int2_t b57 = __builtin_amdgcn_permlane32_swap(w1[5], w1[7], 0, 0);
                int4_t f2 = {b02[0], b13[0], b02[1], b13[1]};
                int4_t f3 = {b46[0], b57[0], b46[1], b57[1]};
                pf[2] = __builtin_bit_cast(half8, f2);
                pf[3] = __builtin_bit_cast(half8, f3);
            }

            // ---- O^T += V^T P^T -------------------------------------------
            __builtin_amdgcn_s_setprio(1);
#pragma unroll
            for (int kc = 0; kc < 4; ++kc) {
                const int r7 = l31 & 7;
                const half8 vf0 = *(const half8*)&VtT[ib][
                    ((l31) * 8 + ((2 * kc + hi) ^ r7)) * 8];
                const half8 vf1 = *(const half8*)&VtT[ib][
                    ((32 + l31) * 8 + ((2 * kc + hi) ^ r7)) * 8];
                o0 = __builtin_amdgcn_mfma_f32_32x32x16_f16(vf0, pf[kc], o0, 0, 0, 0);
                o1 = __builtin_amdgcn_mfma_f32_32x32x16_f16(vf1, pf[kc], o1, 0, 0, 0);
            }
            __builtin_amdgcn_s_setprio(0);
        } // active
    } // kb

    // ---- epilogue: store UNNORMALIZED partials + (m, l) -------------------
    const float lr = l_r + __shfl_xor(l_r, 32);
    const size_t prow = (size_t)(split * 4096 + q0 + l31);
#pragma unroll
    for (int gg = 0; gg < 4; ++gg) {
        half4 wa, wb;
#pragma unroll
        for (int r = 0; r < 4; ++r) {
            wa[r] = (_Float16)o0[4 * gg + r];
            wb[r] = (_Float16)o1[4 * gg + r];
        }
        const size_t base = prow * 1024 + h * HDIM + 8 * gg + 4 * hi;
        *(half4*)&opart[base]      = wa;
        *(half4*)&opart[base + 32] = wb;
    }
    if (hi == 0) {
        float2 ml; ml.x = m_r; ml.y = lr;
        ((float2*)mlpart)[prow * 16 + h] = ml;
    }
}

// ---------------------------------------------------------------------------
// combine: merge the two split-K partials per (row, head); write resh fp16.
// 524288 threads, one half8 of d-values each. ~25 MB traffic, ~6 us.
// ---------------------------------------------------------------------------
__global__ __launch_bounds__(256) void combine(
    const _Float16* __restrict__ opart, const float* __restrict__ mlpart,
    _Float16* __restrict__ resh)
{
    const int idx = blockIdx.x * 256 + threadIdx.x;   // 0..524287
    const int row = idx >> 7;                          // 0..4095
    const int c8  = (idx & 127) * 8;                   // d-offset in the row
    const int h   = c8 >> 6;
    const float2 ml0 = ((const float2*)mlpart)[(size_t)row * 16 + h];
    const float2 ml1 = ((const float2*)mlpart)[(size_t)(4096 + row) * 16 + h];
    const float m  = fmaxf(ml0.x, ml1.x);              // m0 always finite
    const float a0 = __builtin_amdgcn_exp2f(ml0.x - m);
    const float a1 = __builtin_amdgcn_exp2f(ml1.x - m);  // 0 if m1 = -inf
    const float inv = 1.0f / (ml0.y * a0 + ml1.y * a1);  // l0 > 0 always
    const half8 o0 = *(const half8*)&opart[(size_t)row * 1024 + c8];
    const half8 o1 = *(const half8*)&opart[(size_t)(4096 + row) * 1024 + c8];
    half8 w;
#pragma unroll
    for (int jj = 0; jj < 8; ++jj)
        w[jj] = (_Float16)(((float)o0[jj] * a0 + (float)o1[jj] * a1) * inv);
    *(half8*)&resh[(size_t)row * 1024 + c8] = w;
}

// ---------------------------------------------------------------------------
// launch
// ---------------------------------------------------------------------------
extern "C" void kernel_launch(void* const* d_in, const int* in_sizes, int n_in,
                              void* d_out, int out_size, void* d_ws, size_t ws_size,
                              hipStream_t stream)
{
    const float* x    = (const float*)d_in[0];
    const float* Wqkv = (const float*)d_in[2];
    const float* bqkv = (const float*)d_in[3];
    const float* Wp   = (const float*)d_in[4];
    const float* bp   = (const float*)d_in[5];
    float* out = (float*)d_out;

    _Float16* xh  = (_Float16*)d_ws;                 // [4096,1024] fp16  8MB
    _Float16* WTh = xh + (size_t)4096 * 1024;        // [3072,1024] fp16  6MB
    _Float16* qkh = WTh + (size_t)3072 * 1024;       // [4096,2048] fp16 16MB
    _Float16* vtg = qkh + (size_t)4096 * 2048;       // V^T [1024,4096]   8MB
    _Float16* WpT = vtg + (size_t)1024 * 4096;       // [1024,1024] fp16  2MB
    _Float16* opart = WpT + (size_t)1024 * 1024;     // [2,4096,1024] fp16 16MB
    float* mlpart = (float*)(opart + (size_t)2 * 4096 * 1024);  // [2,4096,16,2] f32 1MB
    _Float16* resh = xh;            // alias: x fp16 dead after QKV GEMM

    dim3 blk(256);

    prep<<<dim3(5120), blk, 0, stream>>>(x, Wqkv, Wp, xh, WTh, WpT);

    gemm_qkv<<<dim3(3072 / 128, 4096 / 128), blk, 0, stream>>>(
        xh, WTh, bqkv, qkh, vtg, 1024);

    flash_attn_f16<<<dim3(1024), dim3(256), 0, stream>>>(qkh, vtg, opart, mlpart);

    combine<<<dim3(2048), blk, 0, stream>>>(opart, mlpart, resh);

    gemm_out<<<dim3(1024 / 64, 4096 / 128), blk, 0, stream>>>(
        resh, WpT, bp, out, 1024, 1024);
}